// Round 8
// baseline (135.061 us; speedup 1.0000x reference)
//
#include <hip/hip_runtime.h>
#include <math.h>

#define BB 4
#define TT 4096
#define CC 1024
#define HS 64
#define MM (BB*TT)   // 16384
#define KSPLIT 8

typedef __attribute__((ext_vector_type(8))) short short8;    // 8 bf16 (4 VGPR)
typedef __attribute__((ext_vector_type(4))) float f32x4;     // MFMA acc
typedef __attribute__((ext_vector_type(4))) unsigned short ushort4v;

__device__ __forceinline__ unsigned short f2bf(float f) {   // RNE fp32->bf16
    union { float f; unsigned u; } v; v.f = f;
    return (unsigned short)((v.u + 0x7fffu + ((v.u >> 16) & 1u)) >> 16);
}

// packed RNE fp32x2 -> bf16x2 (bit-identical to f2bf for finite values)
__device__ __forceinline__ unsigned cvt_pk_bf16(float lo, float hi) {
    unsigned r;
    asm("v_cvt_pk_bf16_f32 %0, %1, %2" : "=v"(r) : "v"(lo), "v"(hi));
    return r;
}

// async global->LDS DMA, 16B per lane; LDS dest = wave-uniform base + lane*16
typedef __attribute__((address_space(3))) unsigned short lds_us;
typedef __attribute__((address_space(1))) const unsigned short glb_us;
__device__ __forceinline__ void g2lds16(const unsigned short* g, unsigned short* l) {
    __builtin_amdgcn_global_load_lds((glb_us*)g, (lds_us*)l, 16, 0, 0);
}

// V key-position permutation for the permlane-repacked PV A-fragment.
__device__ __forceinline__ int g4pos(int k) {
    return (k & 32) + 8 * (2 * ((k >> 4) & 1) + ((k >> 2) & 1)) + 4 * ((k >> 3) & 1);
}

// ---------------------------------------------------------------------------
// prep: Wt = W^T bf16, PRE-SWIZZLED + chunk-linearized for qkv's global_load_lds
// (unchanged from R3/R5). Wq pre-scaled by 0.125.
// ---------------------------------------------------------------------------
__global__ __launch_bounds__(256) void prep_kernel(
    const float* __restrict__ Wq, const float* __restrict__ Wk,
    const float* __restrict__ Wv, unsigned short* __restrict__ Wt)
{
    const int which = blockIdx.x >> 4;
    const int k0 = (blockIdx.x & 15) * 64;
    const float* __restrict__ W = (which == 0) ? Wq : (which == 1) ? Wk : Wv;
    const float scale = (which == 0) ? 0.125f : 1.0f;
    __shared__ unsigned short lds[64][65];
    const int t = threadIdx.x;
    #pragma unroll
    for (int i = 0; i < 16; i++) {
        int idx = t + 256 * i;
        int r = idx >> 6, n = idx & 63;           // coalesced read (n fast)
        lds[r][n] = f2bf(W[(size_t)(k0 + r) * 64 + n] * scale);
    }
    __syncthreads();
    #pragma unroll
    for (int i = 0; i < 16; i++) {
        int idx = t + 256 * i;
        int n = idx >> 6, r = idx & 63;           // coalesced write (k fast)
        int nrow = which * 64 + n;
        int kg = k0 + r;
        int ck = kg >> 7, kloc = kg & 127;
        Wt[(size_t)ck * 24576 + (((nrow << 7) + kloc) ^ ((nrow & 7) << 3))] = lds[r][n];
    }
}

// ---------------------------------------------------------------------------
// qkv_mfma: as R7. ONE change: q is stored pre-scaled by log2(e) (single bf16
// rounding, same error class as before) so attn can use raw v_exp_f32 (exp2f)
// with no per-element v_mul — removes 32 VALU/tile-wave in attn.
// ---------------------------------------------------------------------------
__global__ __launch_bounds__(256, 2) void qkv_mfma(
    const float* __restrict__ x, const unsigned short* __restrict__ Wt,
    unsigned short* __restrict__ qb, unsigned short* __restrict__ kbt,
    unsigned short* __restrict__ vTt)
{
    const int rt = blockIdx.x;                 // 32-row tile, 512 blocks
    __shared__ __align__(16) unsigned short xs[32][136];   // padded, reg-staged
    __shared__ __align__(16) unsigned short wsf[192 * 128]; // linear, DMA'd (48KB)

    const int t = threadIdx.x;
    const int w = t >> 6;
    const int lane = t & 63;
    const int quad = lane >> 4;
    const int c = lane & 15;

    const int c2x32 = ((c >> 2) & 1) << 5;     // swizzle: ks-bit flip (in shorts)
    const int quad2 = quad ^ (c & 3);          // swizzle: quad permute

    float4 xreg[4];
    #pragma unroll
    for (int i = 0; i < 4; i++) {              // chunk 0 x
        int idx = t + 256 * i;
        int r = idx >> 5, c4 = (idx & 31) * 4;
        xreg[i] = *(const float4*)(x + (size_t)(rt * 32 + r) * CC + c4);
    }

    f32x4 acc[2][3];
    #pragma unroll
    for (int mt = 0; mt < 2; mt++)
        #pragma unroll
        for (int j = 0; j < 3; j++) acc[mt][j] = (f32x4){0.f, 0.f, 0.f, 0.f};

    for (int ck = 0; ck < 8; ++ck) {
        __syncthreads();                       // prev compute done reading xs/wsf
        // W chunk: 12 x 4KB async DMA (48KB), linear dest, pre-swizzled source
        {
            const unsigned short* wgp = Wt + (size_t)ck * 24576 + t * 8;
            #pragma unroll
            for (int i = 0; i < 12; i++)
                g2lds16(wgp + i * 2048, wsf + (i * 256 + w * 64) * 8);
        }
        // stage x (from regs loaded during previous compute phase)
        #pragma unroll
        for (int i = 0; i < 4; i++) {
            int idx = t + 256 * i;
            int r = idx >> 5, c4 = (idx & 31) * 4;
            ushort4v p = { f2bf(xreg[i].x), f2bf(xreg[i].y), f2bf(xreg[i].z), f2bf(xreg[i].w) };
            *(ushort4v*)&xs[r][c4] = p;
        }
        __syncthreads();                       // drains W DMA + x ds-writes

        // next-chunk x load: issued at top of compute, drains at next barrier
        if (ck + 1 < 8) {
            #pragma unroll
            for (int i = 0; i < 4; i++) {
                int idx = t + 256 * i;
                int r = idx >> 5, c4 = (idx & 31) * 4;
                xreg[i] = *(const float4*)(x + (size_t)(rt * 32 + r) * CC + (ck + 1) * 128 + c4);
            }
        }

        #pragma unroll
        for (int ks = 0; ks < 4; ks++) {
            short8 af[2], bf[3];
            #pragma unroll
            for (int mt = 0; mt < 2; mt++)
                af[mt] = *(const short8*)&xs[16 * mt + c][ks * 32 + quad * 8];
            #pragma unroll
            for (int j = 0; j < 3; j++)
                bf[j] = *(const short8*)&wsf[(16 * (w + 4 * j) + c) * 128 +
                                             ((ks * 32) ^ c2x32) + quad2 * 8];
            #pragma unroll
            for (int mt = 0; mt < 2; mt++)
                #pragma unroll
                for (int j = 0; j < 3; j++)
                    acc[mt][j] = __builtin_amdgcn_mfma_f32_16x16x32_bf16(af[mt], bf[j], acc[mt][j], 0, 0, 0);
        }
    }

    // epilogue: q (x log2e) direct; k -> tiled+swizzled kbt; v -> transposed vTt
    __syncthreads();
    const int b  = rt >> 7;                    // batch
    unsigned short (*vtb)[72] = (unsigned short (*)[72])wsf;  // [d 0..63][t-local 0..31]
    #pragma unroll
    for (int mt = 0; mt < 2; mt++) {
        int grow = rt * 32 + 16 * mt + quad * 4;
        #pragma unroll
        for (int reg = 0; reg < 4; reg++) {
            int trow = grow + reg;                     // global row
            qb[(size_t)trow * HS + 16 * w + c] = f2bf(acc[mt][0][reg] * 1.4426950408889634f);
            int tin = trow & 4095;                     // row within batch
            int kt = tin >> 6, kl = tin & 63;
            int dcol = 16 * w + c;
            kbt[(size_t)(b * 64 + kt) * 4096 + kl * 64 + (dcol ^ ((kl & 7) << 3))]
                = f2bf(acc[mt][1][reg]);
            vtb[16 * w + c][16 * mt + quad * 4 + reg] = f2bf(acc[mt][2][reg]);
        }
    }
    __syncthreads();
    {
        const int t0 = (rt & 127) * 32;
        const int kt = t0 >> 6, half = (t0 >> 5) & 1;
        int d = t >> 2, c8 = (t & 3) * 8;
        short8 v0 = *(const short8*)&vtb[d][c8];
        unsigned short* base = vTt + (size_t)(b * 64 + kt) * 4096 + d * 64;
        const int kl0 = half * 32 + c8;                 // first key of the 8
        const int p0 = g4pos(kl0), p1 = g4pos(kl0 + 4); // permuted positions
        ushort4v lo = { (unsigned short)v0[0], (unsigned short)v0[1],
                        (unsigned short)v0[2], (unsigned short)v0[3] };
        ushort4v hi = { (unsigned short)v0[4], (unsigned short)v0[5],
                        (unsigned short)v0[6], (unsigned short)v0[7] };
        *(ushort4v*)(base + (p0 ^ ((d & 7) << 3))) = lo;
        *(ushort4v*)(base + (p1 ^ ((d & 7) << 3))) = hi;
    }
}

// ---------------------------------------------------------------------------
// attn_mfma: causal flash attention. R8: QT=256 (4 waves x 64 q-rows, 4
// m-frags/wave) -- the 16 K/V ds_read_b128 per tile-wave now feed 64 MFMAs
// (was 32): LDS-read cost per q-row HALVES (the largest remaining instruction
// class per the R7-validated cost model). exp via raw v_exp_f32 (q pre-scaled
// by log2e in qkv) -- no per-element v_mul. QK split into two st-halves so
// s4 live range stays 32 VGPRs (peak ~200, no spill at launch_bounds(256,2)).
// Grid 512 = 2 blocks/CU exact-resident, 2-slot balanced qt map (sum=15/CU,
// heavy-first). In-register softmax/P (R7), swapped QK^T, permlane repack,
// g4pos-permuted V. Fixed shift (=0) -> additive partials; combine normalizes.
// ---------------------------------------------------------------------------
__global__ __launch_bounds__(256, 2) void attn_mfma(
    const unsigned short* __restrict__ qb, const unsigned short* __restrict__ kbt,
    const unsigned short* __restrict__ vTt, float* __restrict__ Opart,
    float* __restrict__ lpart)
{
    const int bid = blockIdx.x;                  // 512 = 16 p x 8 j x 4 b
    const int p   = bid >> 5;                    // dispatch-order qt-group
    const int qt  = (p < 8) ? (15 - p) : (p - 8);   // 2-slot balanced map
    const int rem = bid & 31;
    const int j   = rem >> 2;                    // K-split index 0..7
    const int b   = rem & 3;

    __shared__ __align__(16) unsigned short kv[2][2][4096]; // [buf][K/V][tile] 32 KB

    const int t = threadIdx.x;
    const int w = t >> 6;
    const int lane = t & 63;
    const int quad = lane >> 4;
    const int c = lane & 15;
    const int qrow = qt * 256 + 64 * w;        // wave's first query row (64 rows)

    // swizzled column offsets for frag reads (row&7 == c&7 for all frag rows)
    const int csw0 = (quad * 8) ^ ((c & 7) << 3);
    const int csw1 = (32 + quad * 8) ^ ((c & 7) << 3);

    // Q frags resident in registers: 4 m-frags x 2 d-halves (used as B operand)
    short8 aq[4][2];
    #pragma unroll
    for (int mt = 0; mt < 4; mt++)
        #pragma unroll
        for (int kstep = 0; kstep < 2; kstep++)
            aq[mt][kstep] = *(const short8*)(qb + (size_t)(b * TT + qrow + 16 * mt + c) * HS + kstep * 32 + quad * 8);

    const int lastkt = 4 * qt + 3;             // last key-tile with any work
    const int nkt = (lastkt >= j) ? ((lastkt - j) / KSPLIT) + 1 : 0;
    const unsigned short* Ktiles = kbt + (size_t)b * 64 * 4096;
    const unsigned short* Vtiles = vTt + (size_t)b * 64 * 4096;

// 4 linear 4KB DMA strips: whole 8KB K-tile + 8KB V-tile into kv[BUF]
#define STAGE(BUF, KT) do { \
    size_t o_ = (size_t)(KT) * 4096 + t * 8; \
    g2lds16(Ktiles + o_,        &kv[BUF][0][w * 512]); \
    g2lds16(Ktiles + o_ + 2048, &kv[BUF][0][2048 + w * 512]); \
    g2lds16(Vtiles + o_,        &kv[BUF][1][w * 512]); \
    g2lds16(Vtiles + o_ + 2048, &kv[BUF][1][2048 + w * 512]); } while (0)

    float l[4] = {0.f, 0.f, 0.f, 0.f};
    f32x4 oacc[4][4];
    #pragma unroll
    for (int mt = 0; mt < 4; mt++)
        #pragma unroll
        for (int dt = 0; dt < 4; dt++) oacc[mt][dt] = (f32x4){0.f, 0.f, 0.f, 0.f};

// One st-half (H=0: st{0,1}->ap[.][0]; H=1: st{2,3}->ap[.][1]).
// QK (16 MFMA) -> exp2 (+mask) -> cvt_pk + permlane repack, s4 live = 32 VGPR.
#define QKHALF(CB, H, DOMASK) do { \
    f32x4 s4[4][2]; \
    _Pragma("unroll") \
    for (int mt_ = 0; mt_ < 4; mt_++) { \
        s4[mt_][0] = (f32x4){0.f,0.f,0.f,0.f}; s4[mt_][1] = (f32x4){0.f,0.f,0.f,0.f}; } \
    _Pragma("unroll") \
    for (int sh_ = 0; sh_ < 2; sh_++) { \
        const int stg_ = 2 * (H) + sh_; \
        short8 bf0 = *(const short8*)&kv[CB][0][(16 * stg_ + c) * 64 + csw0]; \
        short8 bf1 = *(const short8*)&kv[CB][0][(16 * stg_ + c) * 64 + csw1]; \
        __builtin_amdgcn_s_setprio(1); \
        _Pragma("unroll") \
        for (int mt_ = 0; mt_ < 4; mt_++) \
            s4[mt_][sh_] = __builtin_amdgcn_mfma_f32_16x16x32_bf16(bf0, aq[mt_][0], s4[mt_][sh_], 0, 0, 0); \
        _Pragma("unroll") \
        for (int mt_ = 0; mt_ < 4; mt_++) \
            s4[mt_][sh_] = __builtin_amdgcn_mfma_f32_16x16x32_bf16(bf1, aq[mt_][1], s4[mt_][sh_], 0, 0, 0); \
        __builtin_amdgcn_s_setprio(0); \
    } \
    _Pragma("unroll") \
    for (int mt_ = 0; mt_ < 4; mt_++) { \
        const int qg_ = qrow + 16 * mt_ + c; (void)qg_; \
        unsigned Wp_[2][2]; \
        _Pragma("unroll") \
        for (int sh_ = 0; sh_ < 2; sh_++) { \
            const int stg_ = 2 * (H) + sh_; (void)stg_; \
            float pv_[4]; \
            _Pragma("unroll") \
            for (int r_ = 0; r_ < 4; r_++) { \
                float e_ = exp2f(s4[mt_][sh_][r_]); \
                if (DOMASK) { \
                    int kg_ = kt0 + 16 * stg_ + 4 * quad + r_; \
                    if (kg_ > qg_) e_ = 0.f; \
                } \
                pv_[r_] = e_; l[mt_] += e_; \
            } \
            Wp_[sh_][0] = cvt_pk_bf16(pv_[0], pv_[1]); \
            Wp_[sh_][1] = cvt_pk_bf16(pv_[2], pv_[3]); \
        } \
        asm volatile("s_nop 1\nv_permlane32_swap_b32 %0, %1\ns_nop 1" : "+v"(Wp_[0][0]), "+v"(Wp_[1][0])); \
        asm volatile("v_permlane32_swap_b32 %0, %1\ns_nop 1" : "+v"(Wp_[0][1]), "+v"(Wp_[1][1])); \
        union UW_ { unsigned u[4]; short8 s; } uu_; \
        uu_.u[0] = Wp_[0][0]; uu_.u[1] = Wp_[0][1]; uu_.u[2] = Wp_[1][0]; uu_.u[3] = Wp_[1][1]; \
        ap[mt_][H] = uu_.s; \
    } } while (0)

    if (nkt > 0) STAGE(0, j);
    __syncthreads();                             // tile 0 staged

    for (int i = 0; i < nkt; i++) {
        const int cb = i & 1;
        const int kt = j + KSPLIT * i;
        const int kt0 = kt * 64;

        // issue next tile's DMA FIRST (overlaps this tile's compute)
        if (i + 1 < nkt) STAGE(cb ^ 1, kt + KSPLIT);

        // wave-uniform skip: tile entirely above this wave's 64 rows
        if (kt0 <= qrow + 63) {
            short8 ap[4][2];
            if (kt >= 4 * qt) {                  // diagonal region: mask
                QKHALF(cb, 0, 1);
                QKHALF(cb, 1, 1);
            } else {                             // interior: no mask
                QKHALF(cb, 0, 0);
                QKHALF(cb, 1, 0);
            }
            // ---- PV accumulate; each bv read feeds 4 m-frag MFMAs
            __builtin_amdgcn_s_setprio(1);
            #pragma unroll
            for (int ks = 0; ks < 2; ks++) {
                const int csw = ks ? csw1 : csw0;
                #pragma unroll
                for (int dt = 0; dt < 4; dt++) {
                    short8 bv = *(const short8*)&kv[cb][1][(16 * dt + c) * 64 + csw];
                    #pragma unroll
                    for (int mt = 0; mt < 4; mt++)
                        oacc[mt][dt] = __builtin_amdgcn_mfma_f32_16x16x32_bf16(ap[mt][ks], bv, oacc[mt][dt], 0, 0, 0);
                }
            }
            __builtin_amdgcn_s_setprio(0);
        }

        __syncthreads();   // ONE barrier/tile: drains DMA, closes compute
    }
#undef QKHALF
#undef STAGE

    // ---- epilogue: sum l over the 4 quads, write unnormalized partials
    #pragma unroll
    for (int mt = 0; mt < 4; mt++) {
        l[mt] += __shfl_xor(l[mt], 16);
        l[mt] += __shfl_xor(l[mt], 32);
    }

    float* __restrict__ Oj = Opart + (size_t)j * MM * HS;
    #pragma unroll
    for (int mt = 0; mt < 4; mt++)
        #pragma unroll
        for (int dt = 0; dt < 4; dt++)
            #pragma unroll
            for (int reg = 0; reg < 4; reg++)
                Oj[(size_t)(b * TT + qrow + 16 * mt + quad * 4 + reg) * HS + 16 * dt + c] = oacc[mt][dt][reg];
    if (lane < 16) {
        #pragma unroll
        for (int mt = 0; mt < 4; mt++)
            lpart[(size_t)j * MM + b * TT + qrow + 16 * mt + lane] = l[mt];
    }
}

// ---------------------------------------------------------------------------
// combine: out = (sum_j O_j) / (sum_j l_j), j=0..7. 262144 float4s, grid 1024.
// ---------------------------------------------------------------------------
__global__ __launch_bounds__(256) void combine_kernel(
    const float* __restrict__ Opart, const float* __restrict__ lpart,
    float* __restrict__ out)
{
    const int id = blockIdx.x * 256 + threadIdx.x;   // 0 .. MM*HS/4-1
    const int row = id >> 4;
    float l = 0.f;
    #pragma unroll
    for (int j = 0; j < KSPLIT; j++) l += lpart[(size_t)j * MM + row];
    const float4* O = (const float4*)Opart;
    const size_t stride = (size_t)MM * HS / 4;
    float4 r = {0.f, 0.f, 0.f, 0.f};
    #pragma unroll
    for (int j = 0; j < KSPLIT; j++) {
        float4 a = O[id + (size_t)j * stride];
        r.x += a.x; r.y += a.y; r.z += a.z; r.w += a.w;
    }
    float inv = 1.f / l;
    r.x *= inv; r.y *= inv; r.z *= inv; r.w *= inv;
    ((float4*)out)[id] = r;
}

extern "C" void kernel_launch(void* const* d_in, const int* in_sizes, int n_in,
                              void* d_out, int out_size, void* d_ws, size_t ws_size,
                              hipStream_t stream) {
    const float* x  = (const float*)d_in[0];
    const float* Wq = (const float*)d_in[1];
    const float* Wk = (const float*)d_in[2];
    const float* Wv = (const float*)d_in[3];
    float* out = (float*)d_out;

    unsigned short* Wt   = (unsigned short*)d_ws;            // 384 KB (swizzled)
    unsigned short* qbuf = Wt + 3 * 64 * 1024;               // 2 MB each
    unsigned short* kbt  = qbuf + (size_t)MM * HS;           // tiled+swizzled K
    unsigned short* vTt  = kbt + (size_t)MM * HS;            // tiled+swizzled+permuted V^T
    float* Opart = (float*)(vTt + (size_t)MM * HS);          // 8 x 4 MB
    float* lpart = Opart + (size_t)KSPLIT * MM * HS;         // 512 KB

    prep_kernel<<<48, 256, 0, stream>>>(Wq, Wk, Wv, Wt);
    qkv_mfma<<<MM / 32, 256, 0, stream>>>(x, Wt, qbuf, kbt, vTt);
    attn_mfma<<<BB * (TT / 256) * KSPLIT, 256, 0, stream>>>(qbuf, kbt, vTt, Opart, lpart);
    combine_kernel<<<1024, 256, 0, stream>>>(Opart, lpart, out);
}

// Round 9
// 134.135 us; speedup vs baseline: 1.0069x; 1.0069x over previous
//
#include <hip/hip_runtime.h>
#include <math.h>

#define BB 4
#define TT 4096
#define CC 1024
#define HS 64
#define MM (BB*TT)   // 16384
#define KSPLIT 8

typedef __attribute__((ext_vector_type(8))) short short8;    // 8 bf16 (4 VGPR)
typedef __attribute__((ext_vector_type(4))) float f32x4;     // MFMA acc
typedef __attribute__((ext_vector_type(4))) unsigned short ushort4v;

__device__ __forceinline__ unsigned short f2bf(float f) {   // RNE fp32->bf16
    union { float f; unsigned u; } v; v.f = f;
    return (unsigned short)((v.u + 0x7fffu + ((v.u >> 16) & 1u)) >> 16);
}

// packed RNE fp32x2 -> bf16x2 (bit-identical to f2bf for finite values)
__device__ __forceinline__ unsigned cvt_pk_bf16(float lo, float hi) {
    unsigned r;
    asm("v_cvt_pk_bf16_f32 %0, %1, %2" : "=v"(r) : "v"(lo), "v"(hi));
    return r;
}

// async global->LDS DMA, 16B per lane; LDS dest = wave-uniform base + lane*16
typedef __attribute__((address_space(3))) unsigned short lds_us;
typedef __attribute__((address_space(1))) const unsigned short glb_us;
__device__ __forceinline__ void g2lds16(const unsigned short* g, unsigned short* l) {
    __builtin_amdgcn_global_load_lds((glb_us*)g, (lds_us*)l, 16, 0, 0);
}

// V key-position permutation for the permlane-repacked PV A-fragment.
__device__ __forceinline__ int g4pos(int k) {
    return (k & 32) + 8 * (2 * ((k >> 4) & 1) + ((k >> 2) & 1)) + 4 * ((k >> 3) & 1);
}

// ---------------------------------------------------------------------------
// prep: Wt = W^T bf16, PRE-SWIZZLED + chunk-linearized for qkv's global_load_lds
// (unchanged from R3/R5). Wq pre-scaled by 0.125.
// ---------------------------------------------------------------------------
__global__ __launch_bounds__(256) void prep_kernel(
    const float* __restrict__ Wq, const float* __restrict__ Wk,
    const float* __restrict__ Wv, unsigned short* __restrict__ Wt)
{
    const int which = blockIdx.x >> 4;
    const int k0 = (blockIdx.x & 15) * 64;
    const float* __restrict__ W = (which == 0) ? Wq : (which == 1) ? Wk : Wv;
    const float scale = (which == 0) ? 0.125f : 1.0f;
    __shared__ unsigned short lds[64][65];
    const int t = threadIdx.x;
    #pragma unroll
    for (int i = 0; i < 16; i++) {
        int idx = t + 256 * i;
        int r = idx >> 6, n = idx & 63;           // coalesced read (n fast)
        lds[r][n] = f2bf(W[(size_t)(k0 + r) * 64 + n] * scale);
    }
    __syncthreads();
    #pragma unroll
    for (int i = 0; i < 16; i++) {
        int idx = t + 256 * i;
        int n = idx >> 6, r = idx & 63;           // coalesced write (k fast)
        int nrow = which * 64 + n;
        int kg = k0 + r;
        int ck = kg >> 7, kloc = kg & 127;
        Wt[(size_t)ck * 24576 + (((nrow << 7) + kloc) ^ ((nrow & 7) << 3))] = lds[r][n];
    }
}

// ---------------------------------------------------------------------------
// qkv_mfma: as R7/R8. q stored pre-scaled by log2(e) (single bf16 rounding)
// so attn uses raw v_exp_f32 (exp2f) with no per-element v_mul.
// K/V emitted tile-major + pre-swizzled (+g4pos-permuted V) for attn's DMA.
// ---------------------------------------------------------------------------
__global__ __launch_bounds__(256, 2) void qkv_mfma(
    const float* __restrict__ x, const unsigned short* __restrict__ Wt,
    unsigned short* __restrict__ qb, unsigned short* __restrict__ kbt,
    unsigned short* __restrict__ vTt)
{
    const int rt = blockIdx.x;                 // 32-row tile, 512 blocks
    __shared__ __align__(16) unsigned short xs[32][136];   // padded, reg-staged
    __shared__ __align__(16) unsigned short wsf[192 * 128]; // linear, DMA'd (48KB)

    const int t = threadIdx.x;
    const int w = t >> 6;
    const int lane = t & 63;
    const int quad = lane >> 4;
    const int c = lane & 15;

    const int c2x32 = ((c >> 2) & 1) << 5;     // swizzle: ks-bit flip (in shorts)
    const int quad2 = quad ^ (c & 3);          // swizzle: quad permute

    float4 xreg[4];
    #pragma unroll
    for (int i = 0; i < 4; i++) {              // chunk 0 x
        int idx = t + 256 * i;
        int r = idx >> 5, c4 = (idx & 31) * 4;
        xreg[i] = *(const float4*)(x + (size_t)(rt * 32 + r) * CC + c4);
    }

    f32x4 acc[2][3];
    #pragma unroll
    for (int mt = 0; mt < 2; mt++)
        #pragma unroll
        for (int j = 0; j < 3; j++) acc[mt][j] = (f32x4){0.f, 0.f, 0.f, 0.f};

    for (int ck = 0; ck < 8; ++ck) {
        __syncthreads();                       // prev compute done reading xs/wsf
        // W chunk: 12 x 4KB async DMA (48KB), linear dest, pre-swizzled source
        {
            const unsigned short* wgp = Wt + (size_t)ck * 24576 + t * 8;
            #pragma unroll
            for (int i = 0; i < 12; i++)
                g2lds16(wgp + i * 2048, wsf + (i * 256 + w * 64) * 8);
        }
        // stage x (from regs loaded during previous compute phase)
        #pragma unroll
        for (int i = 0; i < 4; i++) {
            int idx = t + 256 * i;
            int r = idx >> 5, c4 = (idx & 31) * 4;
            ushort4v p = { f2bf(xreg[i].x), f2bf(xreg[i].y), f2bf(xreg[i].z), f2bf(xreg[i].w) };
            *(ushort4v*)&xs[r][c4] = p;
        }
        __syncthreads();                       // drains W DMA + x ds-writes

        // next-chunk x load: issued at top of compute, drains at next barrier
        if (ck + 1 < 8) {
            #pragma unroll
            for (int i = 0; i < 4; i++) {
                int idx = t + 256 * i;
                int r = idx >> 5, c4 = (idx & 31) * 4;
                xreg[i] = *(const float4*)(x + (size_t)(rt * 32 + r) * CC + (ck + 1) * 128 + c4);
            }
        }

        #pragma unroll
        for (int ks = 0; ks < 4; ks++) {
            short8 af[2], bf[3];
            #pragma unroll
            for (int mt = 0; mt < 2; mt++)
                af[mt] = *(const short8*)&xs[16 * mt + c][ks * 32 + quad * 8];
            #pragma unroll
            for (int j = 0; j < 3; j++)
                bf[j] = *(const short8*)&wsf[(16 * (w + 4 * j) + c) * 128 +
                                             ((ks * 32) ^ c2x32) + quad2 * 8];
            #pragma unroll
            for (int mt = 0; mt < 2; mt++)
                #pragma unroll
                for (int j = 0; j < 3; j++)
                    acc[mt][j] = __builtin_amdgcn_mfma_f32_16x16x32_bf16(af[mt], bf[j], acc[mt][j], 0, 0, 0);
        }
    }

    // epilogue: q (x log2e) direct; k -> tiled+swizzled kbt; v -> transposed vTt
    __syncthreads();
    const int b  = rt >> 7;                    // batch
    unsigned short (*vtb)[72] = (unsigned short (*)[72])wsf;  // [d 0..63][t-local 0..31]
    #pragma unroll
    for (int mt = 0; mt < 2; mt++) {
        int grow = rt * 32 + 16 * mt + quad * 4;
        #pragma unroll
        for (int reg = 0; reg < 4; reg++) {
            int trow = grow + reg;                     // global row
            qb[(size_t)trow * HS + 16 * w + c] = f2bf(acc[mt][0][reg] * 1.4426950408889634f);
            int tin = trow & 4095;                     // row within batch
            int kt = tin >> 6, kl = tin & 63;
            int dcol = 16 * w + c;
            kbt[(size_t)(b * 64 + kt) * 4096 + kl * 64 + (dcol ^ ((kl & 7) << 3))]
                = f2bf(acc[mt][1][reg]);
            vtb[16 * w + c][16 * mt + quad * 4 + reg] = f2bf(acc[mt][2][reg]);
        }
    }
    __syncthreads();
    {
        const int t0 = (rt & 127) * 32;
        const int kt = t0 >> 6, half = (t0 >> 5) & 1;
        int d = t >> 2, c8 = (t & 3) * 8;
        short8 v0 = *(const short8*)&vtb[d][c8];
        unsigned short* base = vTt + (size_t)(b * 64 + kt) * 4096 + d * 64;
        const int kl0 = half * 32 + c8;                 // first key of the 8
        const int p0 = g4pos(kl0), p1 = g4pos(kl0 + 4); // permuted positions
        ushort4v lo = { (unsigned short)v0[0], (unsigned short)v0[1],
                        (unsigned short)v0[2], (unsigned short)v0[3] };
        ushort4v hi = { (unsigned short)v0[4], (unsigned short)v0[5],
                        (unsigned short)v0[6], (unsigned short)v0[7] };
        *(ushort4v*)(base + (p0 ^ ((d & 7) << 3))) = lo;
        *(ushort4v*)(base + (p1 ^ ((d & 7) << 3))) = hi;
    }
}

// ---------------------------------------------------------------------------
// attn_mfma: EXACT R7 structure (session best, 128.6us) with ONE change:
// exp2f instead of __expf (q pre-scaled by log2e in qkv) -- removes 32
// v_mul/tile-wave. R8 lesson baked in: QT stays 128 / 4 blocks/CU; occupancy
// (16 waves/CU covering the per-tile DMA-drain barrier) trumps per-wave
// instruction count. QT=128 (4 waves x 32 q), K-split 8, grid 1024
// all-resident, 4-slot balanced qt map. In-register softmax/P (swapped QK^T,
// cvt_pk + permlane32_swap repack, g4pos-permuted V). Fixed shift (=0) ->
// additive partials; combine normalizes.
// ---------------------------------------------------------------------------
__global__ __launch_bounds__(256, 4) void attn_mfma(
    const unsigned short* __restrict__ qb, const unsigned short* __restrict__ kbt,
    const unsigned short* __restrict__ vTt, float* __restrict__ Opart,
    float* __restrict__ lpart)
{
    const int bid = blockIdx.x;                  // 1024 = 32 p x 8 j x 4 b
    const int p   = bid >> 5;                    // dispatch-order qt-group
    const int qt  = (p < 8) ? (31 - p) : (p < 16) ? (p + 8)
                  : (p < 24) ? (31 - p) : (p - 24);   // 4-slot balanced map
    const int rem = bid & 31;
    const int j   = rem >> 2;                    // K-split index 0..7
    const int b   = rem & 3;

    __shared__ __align__(16) unsigned short kv[2][2][4096]; // [buf][K/V][tile] 32 KB

    const int t = threadIdx.x;
    const int w = t >> 6;
    const int lane = t & 63;
    const int quad = lane >> 4;
    const int c = lane & 15;
    const int qrow = qt * 128 + 32 * w;        // wave's first query row

    // swizzled column offsets for frag reads (row&7 == c&7 for all frag rows)
    const int csw0 = (quad * 8) ^ ((c & 7) << 3);
    const int csw1 = (32 + quad * 8) ^ ((c & 7) << 3);

    // Q frags resident in registers: 2 m-frags x 2 d-halves (used as B operand)
    short8 aq[2][2];
    #pragma unroll
    for (int mt = 0; mt < 2; mt++)
        #pragma unroll
        for (int kstep = 0; kstep < 2; kstep++)
            aq[mt][kstep] = *(const short8*)(qb + (size_t)(b * TT + qrow + 16 * mt + c) * HS + kstep * 32 + quad * 8);

    const int lastkt = 2 * qt + 1;             // last key-tile with any work
    const int nkt = (lastkt >= j) ? ((lastkt - j) / KSPLIT) + 1 : 0;
    const unsigned short* Ktiles = kbt + (size_t)b * 64 * 4096;
    const unsigned short* Vtiles = vTt + (size_t)b * 64 * 4096;

// 4 linear 4KB DMA strips: whole 8KB K-tile + 8KB V-tile into kv[BUF]
#define STAGE(BUF, KT) do { \
    size_t o_ = (size_t)(KT) * 4096 + t * 8; \
    g2lds16(Ktiles + o_,        &kv[BUF][0][w * 512]); \
    g2lds16(Ktiles + o_ + 2048, &kv[BUF][0][2048 + w * 512]); \
    g2lds16(Vtiles + o_,        &kv[BUF][1][w * 512]); \
    g2lds16(Vtiles + o_ + 2048, &kv[BUF][1][2048 + w * 512]); } while (0)

    float l[2] = {0.f, 0.f};
    f32x4 oacc[2][4];
    #pragma unroll
    for (int mt = 0; mt < 2; mt++)
        #pragma unroll
        for (int dt = 0; dt < 4; dt++) oacc[mt][dt] = (f32x4){0.f, 0.f, 0.f, 0.f};

// Full tile: swapped QK^T -> masked exp2 -> in-register repack -> PV.
// S^T layout: lane(quad,c) reg r of s4[mt][st] = S[key=kt0+16st+4quad+r][q=qrow+16mt+c]
#define TILE(CB, DOMASK) do { \
    f32x4 s4[2][4]; \
    _Pragma("unroll") \
    for (int mt_ = 0; mt_ < 2; mt_++) \
        _Pragma("unroll") \
        for (int st_ = 0; st_ < 4; st_++) s4[mt_][st_] = (f32x4){0.f,0.f,0.f,0.f}; \
    _Pragma("unroll") \
    for (int st_ = 0; st_ < 4; st_++) { \
        short8 bf0 = *(const short8*)&kv[CB][0][(16 * st_ + c) * 64 + csw0]; \
        short8 bf1 = *(const short8*)&kv[CB][0][(16 * st_ + c) * 64 + csw1]; \
        __builtin_amdgcn_s_setprio(1); \
        s4[0][st_] = __builtin_amdgcn_mfma_f32_16x16x32_bf16(bf0, aq[0][0], s4[0][st_], 0, 0, 0); \
        s4[1][st_] = __builtin_amdgcn_mfma_f32_16x16x32_bf16(bf0, aq[1][0], s4[1][st_], 0, 0, 0); \
        s4[0][st_] = __builtin_amdgcn_mfma_f32_16x16x32_bf16(bf1, aq[0][1], s4[0][st_], 0, 0, 0); \
        s4[1][st_] = __builtin_amdgcn_mfma_f32_16x16x32_bf16(bf1, aq[1][1], s4[1][st_], 0, 0, 0); \
        __builtin_amdgcn_s_setprio(0); \
    } \
    short8 ap[2][2]; \
    _Pragma("unroll") \
    for (int mt_ = 0; mt_ < 2; mt_++) { \
        const int qg_ = qrow + 16 * mt_ + c; (void)qg_; \
        unsigned Wp[4][2]; \
        _Pragma("unroll") \
        for (int st_ = 0; st_ < 4; st_++) { \
            float pv_[4]; \
            _Pragma("unroll") \
            for (int r_ = 0; r_ < 4; r_++) { \
                float e_ = exp2f(s4[mt_][st_][r_]); \
                if (DOMASK) { \
                    int kg_ = kt0 + 16 * st_ + 4 * quad + r_; \
                    if (kg_ > qg_) e_ = 0.f; \
                } \
                pv_[r_] = e_; l[mt_] += e_; \
            } \
            Wp[st_][0] = cvt_pk_bf16(pv_[0], pv_[1]); \
            Wp[st_][1] = cvt_pk_bf16(pv_[2], pv_[3]); \
        } \
        asm volatile("s_nop 1\nv_permlane32_swap_b32 %0, %1\ns_nop 1" : "+v"(Wp[0][0]), "+v"(Wp[1][0])); \
        asm volatile("v_permlane32_swap_b32 %0, %1\ns_nop 1" : "+v"(Wp[0][1]), "+v"(Wp[1][1])); \
        asm volatile("v_permlane32_swap_b32 %0, %1\ns_nop 1" : "+v"(Wp[2][0]), "+v"(Wp[3][0])); \
        asm volatile("v_permlane32_swap_b32 %0, %1\ns_nop 1" : "+v"(Wp[2][1]), "+v"(Wp[3][1])); \
        union UW_ { unsigned u[4]; short8 s; } u0_, u1_; \
        u0_.u[0] = Wp[0][0]; u0_.u[1] = Wp[0][1]; u0_.u[2] = Wp[1][0]; u0_.u[3] = Wp[1][1]; \
        u1_.u[0] = Wp[2][0]; u1_.u[1] = Wp[2][1]; u1_.u[2] = Wp[3][0]; u1_.u[3] = Wp[3][1]; \
        ap[mt_][0] = u0_.s; ap[mt_][1] = u1_.s; \
    } \
    __builtin_amdgcn_s_setprio(1); \
    _Pragma("unroll") \
    for (int ks_ = 0; ks_ < 2; ks_++) { \
        const int csw_ = ks_ ? csw1 : csw0; \
        _Pragma("unroll") \
        for (int dt_ = 0; dt_ < 4; dt_++) { \
            short8 bv = *(const short8*)&kv[CB][1][(16 * dt_ + c) * 64 + csw_]; \
            oacc[0][dt_] = __builtin_amdgcn_mfma_f32_16x16x32_bf16(ap[0][ks_], bv, oacc[0][dt_], 0, 0, 0); \
            oacc[1][dt_] = __builtin_amdgcn_mfma_f32_16x16x32_bf16(ap[1][ks_], bv, oacc[1][dt_], 0, 0, 0); \
        } \
    } \
    __builtin_amdgcn_s_setprio(0); \
} while (0)

    if (nkt > 0) STAGE(0, j);
    __syncthreads();                             // tile 0 staged

    for (int i = 0; i < nkt; i++) {
        const int cb = i & 1;
        const int kt = j + KSPLIT * i;
        const int kt0 = kt * 64;

        // issue next tile's DMA FIRST (overlaps this tile's compute)
        if (i + 1 < nkt) STAGE(cb ^ 1, kt + KSPLIT);

        // wave-uniform skip: tile entirely above this wave's diagonal
        if (kt0 <= qrow + 31) {
            if (kt >= 2 * qt) {
                TILE(cb, 1);                     // diagonal-adjacent: mask
            } else {
                TILE(cb, 0);                     // interior: no mask
            }
        }

        __syncthreads();   // ONE barrier/tile: drains DMA, closes compute
    }
#undef TILE
#undef STAGE

    // ---- epilogue: sum l over the 4 quads, write unnormalized partials
    l[0] += __shfl_xor(l[0], 16); l[0] += __shfl_xor(l[0], 32);
    l[1] += __shfl_xor(l[1], 16); l[1] += __shfl_xor(l[1], 32);

    float* __restrict__ Oj = Opart + (size_t)j * MM * HS;
    #pragma unroll
    for (int mt = 0; mt < 2; mt++)
        #pragma unroll
        for (int dt = 0; dt < 4; dt++)
            #pragma unroll
            for (int reg = 0; reg < 4; reg++)
                Oj[(size_t)(b * TT + qrow + 16 * mt + quad * 4 + reg) * HS + 16 * dt + c] = oacc[mt][dt][reg];
    if (lane < 16) {
        lpart[(size_t)j * MM + b * TT + qrow + lane]      = l[0];
        lpart[(size_t)j * MM + b * TT + qrow + 16 + lane] = l[1];
    }
}

// ---------------------------------------------------------------------------
// combine: out = (sum_j O_j) / (sum_j l_j), j=0..7. 262144 float4s, grid 1024.
// ---------------------------------------------------------------------------
__global__ __launch_bounds__(256) void combine_kernel(
    const float* __restrict__ Opart, const float* __restrict__ lpart,
    float* __restrict__ out)
{
    const int id = blockIdx.x * 256 + threadIdx.x;   // 0 .. MM*HS/4-1
    const int row = id >> 4;
    float l = 0.f;
    #pragma unroll
    for (int j = 0; j < KSPLIT; j++) l += lpart[(size_t)j * MM + row];
    const float4* O = (const float4*)Opart;
    const size_t stride = (size_t)MM * HS / 4;
    float4 r = {0.f, 0.f, 0.f, 0.f};
    #pragma unroll
    for (int j = 0; j < KSPLIT; j++) {
        float4 a = O[id + (size_t)j * stride];
        r.x += a.x; r.y += a.y; r.z += a.z; r.w += a.w;
    }
    float inv = 1.f / l;
    r.x *= inv; r.y *= inv; r.z *= inv; r.w *= inv;
    ((float4*)out)[id] = r;
}

extern "C" void kernel_launch(void* const* d_in, const int* in_sizes, int n_in,
                              void* d_out, int out_size, void* d_ws, size_t ws_size,
                              hipStream_t stream) {
    const float* x  = (const float*)d_in[0];
    const float* Wq = (const float*)d_in[1];
    const float* Wk = (const float*)d_in[2];
    const float* Wv = (const float*)d_in[3];
    float* out = (float*)d_out;

    unsigned short* Wt   = (unsigned short*)d_ws;            // 384 KB (swizzled)
    unsigned short* qbuf = Wt + 3 * 64 * 1024;               // 2 MB each
    unsigned short* kbt  = qbuf + (size_t)MM * HS;           // tiled+swizzled K
    unsigned short* vTt  = kbt + (size_t)MM * HS;            // tiled+swizzled+permuted V^T
    float* Opart = (float*)(vTt + (size_t)MM * HS);          // 8 x 4 MB
    float* lpart = Opart + (size_t)KSPLIT * MM * HS;         // 512 KB

    prep_kernel<<<48, 256, 0, stream>>>(Wq, Wk, Wv, Wt);
    qkv_mfma<<<MM / 32, 256, 0, stream>>>(x, Wt, qbuf, kbt, vTt);
    attn_mfma<<<BB * (TT / 128) * KSPLIT, 256, 0, stream>>>(qbuf, kbt, vTt, Opart, lpart);
    combine_kernel<<<1024, 256, 0, stream>>>(Opart, lpart, out);
}

// Round 10
// 129.547 us; speedup vs baseline: 1.0426x; 1.0354x over previous
//
#include <hip/hip_runtime.h>
#include <math.h>

#define BB 4
#define TT 4096
#define CC 1024
#define HS 64
#define MM (BB*TT)   // 16384
#define KSPLIT 8

typedef __attribute__((ext_vector_type(8))) short short8;    // 8 bf16 (4 VGPR)
typedef __attribute__((ext_vector_type(4))) float f32x4;     // MFMA acc
typedef __attribute__((ext_vector_type(4))) unsigned short ushort4v;

__device__ __forceinline__ unsigned short f2bf(float f) {   // RNE fp32->bf16
    union { float f; unsigned u; } v; v.f = f;
    return (unsigned short)((v.u + 0x7fffu + ((v.u >> 16) & 1u)) >> 16);
}

// packed RNE fp32x2 -> bf16x2 (bit-identical to f2bf for finite values)
__device__ __forceinline__ unsigned cvt_pk_bf16(float lo, float hi) {
    unsigned r;
    asm("v_cvt_pk_bf16_f32 %0, %1, %2" : "=v"(r) : "v"(lo), "v"(hi));
    return r;
}

// async global->LDS DMA, 16B per lane; LDS dest = wave-uniform base + lane*16
typedef __attribute__((address_space(3))) unsigned short lds_us;
typedef __attribute__((address_space(1))) const unsigned short glb_us;
__device__ __forceinline__ void g2lds16(const unsigned short* g, unsigned short* l) {
    __builtin_amdgcn_global_load_lds((glb_us*)g, (lds_us*)l, 16, 0, 0);
}

// V key-position permutation for the permlane-repacked PV A-fragment.
__device__ __forceinline__ int g4pos(int k) {
    return (k & 32) + 8 * (2 * ((k >> 4) & 1) + ((k >> 2) & 1)) + 4 * ((k >> 3) & 1);
}

// ---------------------------------------------------------------------------
// prep: Wt = W^T bf16, PRE-SWIZZLED + chunk-linearized for qkv's global_load_lds
// (unchanged from R3/R5). Wq pre-scaled by 0.125.
// ---------------------------------------------------------------------------
__global__ __launch_bounds__(256) void prep_kernel(
    const float* __restrict__ Wq, const float* __restrict__ Wk,
    const float* __restrict__ Wv, unsigned short* __restrict__ Wt)
{
    const int which = blockIdx.x >> 4;
    const int k0 = (blockIdx.x & 15) * 64;
    const float* __restrict__ W = (which == 0) ? Wq : (which == 1) ? Wk : Wv;
    const float scale = (which == 0) ? 0.125f : 1.0f;
    __shared__ unsigned short lds[64][65];
    const int t = threadIdx.x;
    #pragma unroll
    for (int i = 0; i < 16; i++) {
        int idx = t + 256 * i;
        int r = idx >> 6, n = idx & 63;           // coalesced read (n fast)
        lds[r][n] = f2bf(W[(size_t)(k0 + r) * 64 + n] * scale);
    }
    __syncthreads();
    #pragma unroll
    for (int i = 0; i < 16; i++) {
        int idx = t + 256 * i;
        int n = idx >> 6, r = idx & 63;           // coalesced write (k fast)
        int nrow = which * 64 + n;
        int kg = k0 + r;
        int ck = kg >> 7, kloc = kg & 127;
        Wt[(size_t)ck * 24576 + (((nrow << 7) + kloc) ^ ((nrow & 7) << 3))] = lds[r][n];
    }
}

// ---------------------------------------------------------------------------
// qkv_mfma: as R7/R9. q stored pre-scaled by log2(e) (single bf16 rounding)
// so attn uses a single raw v_exp_f32 per element (no v_mul, no libm body).
// K/V emitted tile-major + pre-swizzled (+g4pos-permuted V) for attn's DMA.
// ---------------------------------------------------------------------------
__global__ __launch_bounds__(256, 2) void qkv_mfma(
    const float* __restrict__ x, const unsigned short* __restrict__ Wt,
    unsigned short* __restrict__ qb, unsigned short* __restrict__ kbt,
    unsigned short* __restrict__ vTt)
{
    const int rt = blockIdx.x;                 // 32-row tile, 512 blocks
    __shared__ __align__(16) unsigned short xs[32][136];   // padded, reg-staged
    __shared__ __align__(16) unsigned short wsf[192 * 128]; // linear, DMA'd (48KB)

    const int t = threadIdx.x;
    const int w = t >> 6;
    const int lane = t & 63;
    const int quad = lane >> 4;
    const int c = lane & 15;

    const int c2x32 = ((c >> 2) & 1) << 5;     // swizzle: ks-bit flip (in shorts)
    const int quad2 = quad ^ (c & 3);          // swizzle: quad permute

    float4 xreg[4];
    #pragma unroll
    for (int i = 0; i < 4; i++) {              // chunk 0 x
        int idx = t + 256 * i;
        int r = idx >> 5, c4 = (idx & 31) * 4;
        xreg[i] = *(const float4*)(x + (size_t)(rt * 32 + r) * CC + c4);
    }

    f32x4 acc[2][3];
    #pragma unroll
    for (int mt = 0; mt < 2; mt++)
        #pragma unroll
        for (int j = 0; j < 3; j++) acc[mt][j] = (f32x4){0.f, 0.f, 0.f, 0.f};

    for (int ck = 0; ck < 8; ++ck) {
        __syncthreads();                       // prev compute done reading xs/wsf
        // W chunk: 12 x 4KB async DMA (48KB), linear dest, pre-swizzled source
        {
            const unsigned short* wgp = Wt + (size_t)ck * 24576 + t * 8;
            #pragma unroll
            for (int i = 0; i < 12; i++)
                g2lds16(wgp + i * 2048, wsf + (i * 256 + w * 64) * 8);
        }
        // stage x (from regs loaded during previous compute phase)
        #pragma unroll
        for (int i = 0; i < 4; i++) {
            int idx = t + 256 * i;
            int r = idx >> 5, c4 = (idx & 31) * 4;
            ushort4v p = { f2bf(xreg[i].x), f2bf(xreg[i].y), f2bf(xreg[i].z), f2bf(xreg[i].w) };
            *(ushort4v*)&xs[r][c4] = p;
        }
        __syncthreads();                       // drains W DMA + x ds-writes

        // next-chunk x load: issued at top of compute, drains at next barrier
        if (ck + 1 < 8) {
            #pragma unroll
            for (int i = 0; i < 4; i++) {
                int idx = t + 256 * i;
                int r = idx >> 5, c4 = (idx & 31) * 4;
                xreg[i] = *(const float4*)(x + (size_t)(rt * 32 + r) * CC + (ck + 1) * 128 + c4);
            }
        }

        #pragma unroll
        for (int ks = 0; ks < 4; ks++) {
            short8 af[2], bf[3];
            #pragma unroll
            for (int mt = 0; mt < 2; mt++)
                af[mt] = *(const short8*)&xs[16 * mt + c][ks * 32 + quad * 8];
            #pragma unroll
            for (int j = 0; j < 3; j++)
                bf[j] = *(const short8*)&wsf[(16 * (w + 4 * j) + c) * 128 +
                                             ((ks * 32) ^ c2x32) + quad2 * 8];
            #pragma unroll
            for (int mt = 0; mt < 2; mt++)
                #pragma unroll
                for (int j = 0; j < 3; j++)
                    acc[mt][j] = __builtin_amdgcn_mfma_f32_16x16x32_bf16(af[mt], bf[j], acc[mt][j], 0, 0, 0);
        }
    }

    // epilogue: q (x log2e) direct; k -> tiled+swizzled kbt; v -> transposed vTt
    __syncthreads();
    const int b  = rt >> 7;                    // batch
    unsigned short (*vtb)[72] = (unsigned short (*)[72])wsf;  // [d 0..63][t-local 0..31]
    #pragma unroll
    for (int mt = 0; mt < 2; mt++) {
        int grow = rt * 32 + 16 * mt + quad * 4;
        #pragma unroll
        for (int reg = 0; reg < 4; reg++) {
            int trow = grow + reg;                     // global row
            qb[(size_t)trow * HS + 16 * w + c] = f2bf(acc[mt][0][reg] * 1.4426950408889634f);
            int tin = trow & 4095;                     // row within batch
            int kt = tin >> 6, kl = tin & 63;
            int dcol = 16 * w + c;
            kbt[(size_t)(b * 64 + kt) * 4096 + kl * 64 + (dcol ^ ((kl & 7) << 3))]
                = f2bf(acc[mt][1][reg]);
            vtb[16 * w + c][16 * mt + quad * 4 + reg] = f2bf(acc[mt][2][reg]);
        }
    }
    __syncthreads();
    {
        const int t0 = (rt & 127) * 32;
        const int kt = t0 >> 6, half = (t0 >> 5) & 1;
        int d = t >> 2, c8 = (t & 3) * 8;
        short8 v0 = *(const short8*)&vtb[d][c8];
        unsigned short* base = vTt + (size_t)(b * 64 + kt) * 4096 + d * 64;
        const int kl0 = half * 32 + c8;                 // first key of the 8
        const int p0 = g4pos(kl0), p1 = g4pos(kl0 + 4); // permuted positions
        ushort4v lo = { (unsigned short)v0[0], (unsigned short)v0[1],
                        (unsigned short)v0[2], (unsigned short)v0[3] };
        ushort4v hi = { (unsigned short)v0[4], (unsigned short)v0[5],
                        (unsigned short)v0[6], (unsigned short)v0[7] };
        *(ushort4v*)(base + (p0 ^ ((d & 7) << 3))) = lo;
        *(ushort4v*)(base + (p1 ^ ((d & 7) << 3))) = hi;
    }
}

// ---------------------------------------------------------------------------
// attn_mfma: EXACT R7 structure (session best, 128.6us) with the exp path
// fixed: __builtin_amdgcn_exp2f = exactly ONE raw v_exp_f32 per element
// (R9 lesson: plain exp2f() lowers to OCML's precise multi-instruction
// __ocml_exp2_f32 -- a 5.5us regression; __expf was native v_mul+v_exp).
// q is pre-scaled by log2e in qkv, so this is 1 instr/element vs R7's 2.
// QT=128 (4 waves x 32 q), 4 blocks/CU (R8 lesson: occupancy >= 4 blocks/CU
// is load-bearing), K-split 8, grid 1024 all-resident, 4-slot balanced map.
// In-register softmax/P (swapped QK^T, cvt_pk + permlane32_swap repack,
// g4pos-permuted V). Fixed shift (=0) -> additive partials; combine norms.
// ---------------------------------------------------------------------------
__global__ __launch_bounds__(256, 4) void attn_mfma(
    const unsigned short* __restrict__ qb, const unsigned short* __restrict__ kbt,
    const unsigned short* __restrict__ vTt, float* __restrict__ Opart,
    float* __restrict__ lpart)
{
    const int bid = blockIdx.x;                  // 1024 = 32 p x 8 j x 4 b
    const int p   = bid >> 5;                    // dispatch-order qt-group
    const int qt  = (p < 8) ? (31 - p) : (p < 16) ? (p + 8)
                  : (p < 24) ? (31 - p) : (p - 24);   // 4-slot balanced map
    const int rem = bid & 31;
    const int j   = rem >> 2;                    // K-split index 0..7
    const int b   = rem & 3;

    __shared__ __align__(16) unsigned short kv[2][2][4096]; // [buf][K/V][tile] 32 KB

    const int t = threadIdx.x;
    const int w = t >> 6;
    const int lane = t & 63;
    const int quad = lane >> 4;
    const int c = lane & 15;
    const int qrow = qt * 128 + 32 * w;        // wave's first query row

    // swizzled column offsets for frag reads (row&7 == c&7 for all frag rows)
    const int csw0 = (quad * 8) ^ ((c & 7) << 3);
    const int csw1 = (32 + quad * 8) ^ ((c & 7) << 3);

    // Q frags resident in registers: 2 m-frags x 2 d-halves (used as B operand)
    short8 aq[2][2];
    #pragma unroll
    for (int mt = 0; mt < 2; mt++)
        #pragma unroll
        for (int kstep = 0; kstep < 2; kstep++)
            aq[mt][kstep] = *(const short8*)(qb + (size_t)(b * TT + qrow + 16 * mt + c) * HS + kstep * 32 + quad * 8);

    const int lastkt = 2 * qt + 1;             // last key-tile with any work
    const int nkt = (lastkt >= j) ? ((lastkt - j) / KSPLIT) + 1 : 0;
    const unsigned short* Ktiles = kbt + (size_t)b * 64 * 4096;
    const unsigned short* Vtiles = vTt + (size_t)b * 64 * 4096;

// 4 linear 4KB DMA strips: whole 8KB K-tile + 8KB V-tile into kv[BUF]
#define STAGE(BUF, KT) do { \
    size_t o_ = (size_t)(KT) * 4096 + t * 8; \
    g2lds16(Ktiles + o_,        &kv[BUF][0][w * 512]); \
    g2lds16(Ktiles + o_ + 2048, &kv[BUF][0][2048 + w * 512]); \
    g2lds16(Vtiles + o_,        &kv[BUF][1][w * 512]); \
    g2lds16(Vtiles + o_ + 2048, &kv[BUF][1][2048 + w * 512]); } while (0)

    float l[2] = {0.f, 0.f};
    f32x4 oacc[2][4];
    #pragma unroll
    for (int mt = 0; mt < 2; mt++)
        #pragma unroll
        for (int dt = 0; dt < 4; dt++) oacc[mt][dt] = (f32x4){0.f, 0.f, 0.f, 0.f};

// Full tile: swapped QK^T -> masked exp2 -> in-register repack -> PV.
// S^T layout: lane(quad,c) reg r of s4[mt][st] = S[key=kt0+16st+4quad+r][q=qrow+16mt+c]
#define TILE(CB, DOMASK) do { \
    f32x4 s4[2][4]; \
    _Pragma("unroll") \
    for (int mt_ = 0; mt_ < 2; mt_++) \
        _Pragma("unroll") \
        for (int st_ = 0; st_ < 4; st_++) s4[mt_][st_] = (f32x4){0.f,0.f,0.f,0.f}; \
    _Pragma("unroll") \
    for (int st_ = 0; st_ < 4; st_++) { \
        short8 bf0 = *(const short8*)&kv[CB][0][(16 * st_ + c) * 64 + csw0]; \
        short8 bf1 = *(const short8*)&kv[CB][0][(16 * st_ + c) * 64 + csw1]; \
        __builtin_amdgcn_s_setprio(1); \
        s4[0][st_] = __builtin_amdgcn_mfma_f32_16x16x32_bf16(bf0, aq[0][0], s4[0][st_], 0, 0, 0); \
        s4[1][st_] = __builtin_amdgcn_mfma_f32_16x16x32_bf16(bf0, aq[1][0], s4[1][st_], 0, 0, 0); \
        s4[0][st_] = __builtin_amdgcn_mfma_f32_16x16x32_bf16(bf1, aq[0][1], s4[0][st_], 0, 0, 0); \
        s4[1][st_] = __builtin_amdgcn_mfma_f32_16x16x32_bf16(bf1, aq[1][1], s4[1][st_], 0, 0, 0); \
        __builtin_amdgcn_s_setprio(0); \
    } \
    short8 ap[2][2]; \
    _Pragma("unroll") \
    for (int mt_ = 0; mt_ < 2; mt_++) { \
        const int qg_ = qrow + 16 * mt_ + c; (void)qg_; \
        unsigned Wp[4][2]; \
        _Pragma("unroll") \
        for (int st_ = 0; st_ < 4; st_++) { \
            float pv_[4]; \
            _Pragma("unroll") \
            for (int r_ = 0; r_ < 4; r_++) { \
                float e_ = __builtin_amdgcn_exp2f(s4[mt_][st_][r_]); \
                if (DOMASK) { \
                    int kg_ = kt0 + 16 * st_ + 4 * quad + r_; \
                    if (kg_ > qg_) e_ = 0.f; \
                } \
                pv_[r_] = e_; l[mt_] += e_; \
            } \
            Wp[st_][0] = cvt_pk_bf16(pv_[0], pv_[1]); \
            Wp[st_][1] = cvt_pk_bf16(pv_[2], pv_[3]); \
        } \
        asm volatile("s_nop 1\nv_permlane32_swap_b32 %0, %1\ns_nop 1" : "+v"(Wp[0][0]), "+v"(Wp[1][0])); \
        asm volatile("v_permlane32_swap_b32 %0, %1\ns_nop 1" : "+v"(Wp[0][1]), "+v"(Wp[1][1])); \
        asm volatile("v_permlane32_swap_b32 %0, %1\ns_nop 1" : "+v"(Wp[2][0]), "+v"(Wp[3][0])); \
        asm volatile("v_permlane32_swap_b32 %0, %1\ns_nop 1" : "+v"(Wp[2][1]), "+v"(Wp[3][1])); \
        union UW_ { unsigned u[4]; short8 s; } u0_, u1_; \
        u0_.u[0] = Wp[0][0]; u0_.u[1] = Wp[0][1]; u0_.u[2] = Wp[1][0]; u0_.u[3] = Wp[1][1]; \
        u1_.u[0] = Wp[2][0]; u1_.u[1] = Wp[2][1]; u1_.u[2] = Wp[3][0]; u1_.u[3] = Wp[3][1]; \
        ap[mt_][0] = u0_.s; ap[mt_][1] = u1_.s; \
    } \
    __builtin_amdgcn_s_setprio(1); \
    _Pragma("unroll") \
    for (int ks_ = 0; ks_ < 2; ks_++) { \
        const int csw_ = ks_ ? csw1 : csw0; \
        _Pragma("unroll") \
        for (int dt_ = 0; dt_ < 4; dt_++) { \
            short8 bv = *(const short8*)&kv[CB][1][(16 * dt_ + c) * 64 + csw_]; \
            oacc[0][dt_] = __builtin_amdgcn_mfma_f32_16x16x32_bf16(ap[0][ks_], bv, oacc[0][dt_], 0, 0, 0); \
            oacc[1][dt_] = __builtin_amdgcn_mfma_f32_16x16x32_bf16(ap[1][ks_], bv, oacc[1][dt_], 0, 0, 0); \
        } \
    } \
    __builtin_amdgcn_s_setprio(0); \
} while (0)

    if (nkt > 0) STAGE(0, j);
    __syncthreads();                             // tile 0 staged

    for (int i = 0; i < nkt; i++) {
        const int cb = i & 1;
        const int kt = j + KSPLIT * i;
        const int kt0 = kt * 64;

        // issue next tile's DMA FIRST (overlaps this tile's compute)
        if (i + 1 < nkt) STAGE(cb ^ 1, kt + KSPLIT);

        // wave-uniform skip: tile entirely above this wave's diagonal
        if (kt0 <= qrow + 31) {
            if (kt >= 2 * qt) {
                TILE(cb, 1);                     // diagonal-adjacent: mask
            } else {
                TILE(cb, 0);                     // interior: no mask
            }
        }

        __syncthreads();   // ONE barrier/tile: drains DMA, closes compute
    }
#undef TILE
#undef STAGE

    // ---- epilogue: sum l over the 4 quads, write unnormalized partials
    l[0] += __shfl_xor(l[0], 16); l[0] += __shfl_xor(l[0], 32);
    l[1] += __shfl_xor(l[1], 16); l[1] += __shfl_xor(l[1], 32);

    float* __restrict__ Oj = Opart + (size_t)j * MM * HS;
    #pragma unroll
    for (int mt = 0; mt < 2; mt++)
        #pragma unroll
        for (int dt = 0; dt < 4; dt++)
            #pragma unroll
            for (int reg = 0; reg < 4; reg++)
                Oj[(size_t)(b * TT + qrow + 16 * mt + quad * 4 + reg) * HS + 16 * dt + c] = oacc[mt][dt][reg];
    if (lane < 16) {
        lpart[(size_t)j * MM + b * TT + qrow + lane]      = l[0];
        lpart[(size_t)j * MM + b * TT + qrow + 16 + lane] = l[1];
    }
}

// ---------------------------------------------------------------------------
// combine: out = (sum_j O_j) / (sum_j l_j), j=0..7. 262144 float4s, grid 1024.
// ---------------------------------------------------------------------------
__global__ __launch_bounds__(256) void combine_kernel(
    const float* __restrict__ Opart, const float* __restrict__ lpart,
    float* __restrict__ out)
{
    const int id = blockIdx.x * 256 + threadIdx.x;   // 0 .. MM*HS/4-1
    const int row = id >> 4;
    float l = 0.f;
    #pragma unroll
    for (int j = 0; j < KSPLIT; j++) l += lpart[(size_t)j * MM + row];
    const float4* O = (const float4*)Opart;
    const size_t stride = (size_t)MM * HS / 4;
    float4 r = {0.f, 0.f, 0.f, 0.f};
    #pragma unroll
    for (int j = 0; j < KSPLIT; j++) {
        float4 a = O[id + (size_t)j * stride];
        r.x += a.x; r.y += a.y; r.z += a.z; r.w += a.w;
    }
    float inv = 1.f / l;
    r.x *= inv; r.y *= inv; r.z *= inv; r.w *= inv;
    ((float4*)out)[id] = r;
}

extern "C" void kernel_launch(void* const* d_in, const int* in_sizes, int n_in,
                              void* d_out, int out_size, void* d_ws, size_t ws_size,
                              hipStream_t stream) {
    const float* x  = (const float*)d_in[0];
    const float* Wq = (const float*)d_in[1];
    const float* Wk = (const float*)d_in[2];
    const float* Wv = (const float*)d_in[3];
    float* out = (float*)d_out;

    unsigned short* Wt   = (unsigned short*)d_ws;            // 384 KB (swizzled)
    unsigned short* qbuf = Wt + 3 * 64 * 1024;               // 2 MB each
    unsigned short* kbt  = qbuf + (size_t)MM * HS;           // tiled+swizzled K
    unsigned short* vTt  = kbt + (size_t)MM * HS;            // tiled+swizzled+permuted V^T
    float* Opart = (float*)(vTt + (size_t)MM * HS);          // 8 x 4 MB
    float* lpart = Opart + (size_t)KSPLIT * MM * HS;         // 512 KB

    prep_kernel<<<48, 256, 0, stream>>>(Wq, Wk, Wv, Wt);
    qkv_mfma<<<MM / 32, 256, 0, stream>>>(x, Wt, qbuf, kbt, vTt);
    attn_mfma<<<BB * (TT / 128) * KSPLIT, 256, 0, stream>>>(qbuf, kbt, vTt, Opart, lpart);
    combine_kernel<<<1024, 256, 0, stream>>>(Opart, lpart, out);
}

// Round 11
// 126.701 us; speedup vs baseline: 1.0660x; 1.0225x over previous
//
#include <hip/hip_runtime.h>
#include <math.h>

#define BB 4
#define TT 4096
#define CC 1024
#define HS 64
#define MM (BB*TT)   // 16384
#define KSPLIT 8

typedef __attribute__((ext_vector_type(8))) short short8;    // 8 bf16 (4 VGPR)
typedef __attribute__((ext_vector_type(4))) float f32x4;     // MFMA acc
typedef __attribute__((ext_vector_type(4))) unsigned short ushort4v;

__device__ __forceinline__ unsigned short f2bf(float f) {   // RNE fp32->bf16
    union { float f; unsigned u; } v; v.f = f;
    return (unsigned short)((v.u + 0x7fffu + ((v.u >> 16) & 1u)) >> 16);
}

// packed RNE fp32x2 -> bf16x2 (bit-identical to f2bf for finite values)
__device__ __forceinline__ unsigned cvt_pk_bf16(float lo, float hi) {
    unsigned r;
    asm("v_cvt_pk_bf16_f32 %0, %1, %2" : "=v"(r) : "v"(lo), "v"(hi));
    return r;
}

// async global->LDS DMA, 16B per lane; LDS dest = wave-uniform base + lane*16
typedef __attribute__((address_space(3))) unsigned short lds_us;
typedef __attribute__((address_space(1))) const unsigned short glb_us;
__device__ __forceinline__ void g2lds16(const unsigned short* g, unsigned short* l) {
    __builtin_amdgcn_global_load_lds((glb_us*)g, (lds_us*)l, 16, 0, 0);
}

// V key-position permutation for the permlane-repacked PV A-fragment.
__device__ __forceinline__ int g4pos(int k) {
    return (k & 32) + 8 * (2 * ((k >> 4) & 1) + ((k >> 2) & 1)) + 4 * ((k >> 3) & 1);
}

// ---------------------------------------------------------------------------
// prep: Wt = W^T bf16, PRE-SWIZZLED + chunk-linearized for qkv's global_load_lds
// (unchanged from R3/R5). Wq pre-scaled by 0.125.
// ---------------------------------------------------------------------------
__global__ __launch_bounds__(256) void prep_kernel(
    const float* __restrict__ Wq, const float* __restrict__ Wk,
    const float* __restrict__ Wv, unsigned short* __restrict__ Wt)
{
    const int which = blockIdx.x >> 4;
    const int k0 = (blockIdx.x & 15) * 64;
    const float* __restrict__ W = (which == 0) ? Wq : (which == 1) ? Wk : Wv;
    const float scale = (which == 0) ? 0.125f : 1.0f;
    __shared__ unsigned short lds[64][65];
    const int t = threadIdx.x;
    #pragma unroll
    for (int i = 0; i < 16; i++) {
        int idx = t + 256 * i;
        int r = idx >> 6, n = idx & 63;           // coalesced read (n fast)
        lds[r][n] = f2bf(W[(size_t)(k0 + r) * 64 + n] * scale);
    }
    __syncthreads();
    #pragma unroll
    for (int i = 0; i < 16; i++) {
        int idx = t + 256 * i;
        int n = idx >> 6, r = idx & 63;           // coalesced write (k fast)
        int nrow = which * 64 + n;
        int kg = k0 + r;
        int ck = kg >> 7, kloc = kg & 127;
        Wt[(size_t)ck * 24576 + (((nrow << 7) + kloc) ^ ((nrow & 7) << 3))] = lds[r][n];
    }
}

// ---------------------------------------------------------------------------
// qkv_mfma: as R7/R10. q stored pre-scaled by log2(e) (single bf16 rounding)
// so attn uses a single raw v_exp_f32 per element.
// K/V emitted tile-major + pre-swizzled (+g4pos-permuted V) for attn's DMA.
// ---------------------------------------------------------------------------
__global__ __launch_bounds__(256, 2) void qkv_mfma(
    const float* __restrict__ x, const unsigned short* __restrict__ Wt,
    unsigned short* __restrict__ qb, unsigned short* __restrict__ kbt,
    unsigned short* __restrict__ vTt)
{
    const int rt = blockIdx.x;                 // 32-row tile, 512 blocks
    __shared__ __align__(16) unsigned short xs[32][136];   // padded, reg-staged
    __shared__ __align__(16) unsigned short wsf[192 * 128]; // linear, DMA'd (48KB)

    const int t = threadIdx.x;
    const int w = t >> 6;
    const int lane = t & 63;
    const int quad = lane >> 4;
    const int c = lane & 15;

    const int c2x32 = ((c >> 2) & 1) << 5;     // swizzle: ks-bit flip (in shorts)
    const int quad2 = quad ^ (c & 3);          // swizzle: quad permute

    float4 xreg[4];
    #pragma unroll
    for (int i = 0; i < 4; i++) {              // chunk 0 x
        int idx = t + 256 * i;
        int r = idx >> 5, c4 = (idx & 31) * 4;
        xreg[i] = *(const float4*)(x + (size_t)(rt * 32 + r) * CC + c4);
    }

    f32x4 acc[2][3];
    #pragma unroll
    for (int mt = 0; mt < 2; mt++)
        #pragma unroll
        for (int j = 0; j < 3; j++) acc[mt][j] = (f32x4){0.f, 0.f, 0.f, 0.f};

    for (int ck = 0; ck < 8; ++ck) {
        __syncthreads();                       // prev compute done reading xs/wsf
        // W chunk: 12 x 4KB async DMA (48KB), linear dest, pre-swizzled source
        {
            const unsigned short* wgp = Wt + (size_t)ck * 24576 + t * 8;
            #pragma unroll
            for (int i = 0; i < 12; i++)
                g2lds16(wgp + i * 2048, wsf + (i * 256 + w * 64) * 8);
        }
        // stage x (from regs loaded during previous compute phase)
        #pragma unroll
        for (int i = 0; i < 4; i++) {
            int idx = t + 256 * i;
            int r = idx >> 5, c4 = (idx & 31) * 4;
            ushort4v p = { f2bf(xreg[i].x), f2bf(xreg[i].y), f2bf(xreg[i].z), f2bf(xreg[i].w) };
            *(ushort4v*)&xs[r][c4] = p;
        }
        __syncthreads();                       // drains W DMA + x ds-writes

        // next-chunk x load: issued at top of compute, drains at next barrier
        if (ck + 1 < 8) {
            #pragma unroll
            for (int i = 0; i < 4; i++) {
                int idx = t + 256 * i;
                int r = idx >> 5, c4 = (idx & 31) * 4;
                xreg[i] = *(const float4*)(x + (size_t)(rt * 32 + r) * CC + (ck + 1) * 128 + c4);
            }
        }

        #pragma unroll
        for (int ks = 0; ks < 4; ks++) {
            short8 af[2], bf[3];
            #pragma unroll
            for (int mt = 0; mt < 2; mt++)
                af[mt] = *(const short8*)&xs[16 * mt + c][ks * 32 + quad * 8];
            #pragma unroll
            for (int j = 0; j < 3; j++)
                bf[j] = *(const short8*)&wsf[(16 * (w + 4 * j) + c) * 128 +
                                             ((ks * 32) ^ c2x32) + quad2 * 8];
            #pragma unroll
            for (int mt = 0; mt < 2; mt++)
                #pragma unroll
                for (int j = 0; j < 3; j++)
                    acc[mt][j] = __builtin_amdgcn_mfma_f32_16x16x32_bf16(af[mt], bf[j], acc[mt][j], 0, 0, 0);
        }
    }

    // epilogue: q (x log2e) direct; k -> tiled+swizzled kbt; v -> transposed vTt
    __syncthreads();
    const int b  = rt >> 7;                    // batch
    unsigned short (*vtb)[72] = (unsigned short (*)[72])wsf;  // [d 0..63][t-local 0..31]
    #pragma unroll
    for (int mt = 0; mt < 2; mt++) {
        int grow = rt * 32 + 16 * mt + quad * 4;
        #pragma unroll
        for (int reg = 0; reg < 4; reg++) {
            int trow = grow + reg;                     // global row
            qb[(size_t)trow * HS + 16 * w + c] = f2bf(acc[mt][0][reg] * 1.4426950408889634f);
            int tin = trow & 4095;                     // row within batch
            int kt = tin >> 6, kl = tin & 63;
            int dcol = 16 * w + c;
            kbt[(size_t)(b * 64 + kt) * 4096 + kl * 64 + (dcol ^ ((kl & 7) << 3))]
                = f2bf(acc[mt][1][reg]);
            vtb[16 * w + c][16 * mt + quad * 4 + reg] = f2bf(acc[mt][2][reg]);
        }
    }
    __syncthreads();
    {
        const int t0 = (rt & 127) * 32;
        const int kt = t0 >> 6, half = (t0 >> 5) & 1;
        int d = t >> 2, c8 = (t & 3) * 8;
        short8 v0 = *(const short8*)&vtb[d][c8];
        unsigned short* base = vTt + (size_t)(b * 64 + kt) * 4096 + d * 64;
        const int kl0 = half * 32 + c8;                 // first key of the 8
        const int p0 = g4pos(kl0), p1 = g4pos(kl0 + 4); // permuted positions
        ushort4v lo = { (unsigned short)v0[0], (unsigned short)v0[1],
                        (unsigned short)v0[2], (unsigned short)v0[3] };
        ushort4v hi = { (unsigned short)v0[4], (unsigned short)v0[5],
                        (unsigned short)v0[6], (unsigned short)v0[7] };
        *(ushort4v*)(base + (p0 ^ ((d & 7) << 3))) = lo;
        *(ushort4v*)(base + (p1 ^ ((d & 7) << 3))) = hi;
    }
}

// ---------------------------------------------------------------------------
// attn_mfma: EXACT R10 structure (== R7 + builtin v_exp) with ONE change:
// O-partials stored as BF16 (RNE f2bf) -- halves attn's partial-write stream
// (32 -> 16 MB, relieving per-XCD L2 pressure on K/V) and halves combine's
// read traffic. Numerics bound: added out-error <= 0.002*Sum|O_j|/l ~ 1e-4
// (late rows) .. 0.006 (worst early rows) -- below the existing bf16-dominated
// 0.0156 error scale. l partials stay fp32.
// QT=128 (4 waves x 32 q), 4 blocks/CU, K-split 8, grid 1024 all-resident,
// 4-slot balanced map. In-register softmax/P (swapped QK^T, cvt_pk +
// permlane32_swap repack, g4pos-permuted V). Fixed shift (=0) -> additive.
// ---------------------------------------------------------------------------
__global__ __launch_bounds__(256, 4) void attn_mfma(
    const unsigned short* __restrict__ qb, const unsigned short* __restrict__ kbt,
    const unsigned short* __restrict__ vTt, unsigned short* __restrict__ Opart,
    float* __restrict__ lpart)
{
    const int bid = blockIdx.x;                  // 1024 = 32 p x 8 j x 4 b
    const int p   = bid >> 5;                    // dispatch-order qt-group
    const int qt  = (p < 8) ? (31 - p) : (p < 16) ? (p + 8)
                  : (p < 24) ? (31 - p) : (p - 24);   // 4-slot balanced map
    const int rem = bid & 31;
    const int j   = rem >> 2;                    // K-split index 0..7
    const int b   = rem & 3;

    __shared__ __align__(16) unsigned short kv[2][2][4096]; // [buf][K/V][tile] 32 KB

    const int t = threadIdx.x;
    const int w = t >> 6;
    const int lane = t & 63;
    const int quad = lane >> 4;
    const int c = lane & 15;
    const int qrow = qt * 128 + 32 * w;        // wave's first query row

    // swizzled column offsets for frag reads (row&7 == c&7 for all frag rows)
    const int csw0 = (quad * 8) ^ ((c & 7) << 3);
    const int csw1 = (32 + quad * 8) ^ ((c & 7) << 3);

    // Q frags resident in registers: 2 m-frags x 2 d-halves (used as B operand)
    short8 aq[2][2];
    #pragma unroll
    for (int mt = 0; mt < 2; mt++)
        #pragma unroll
        for (int kstep = 0; kstep < 2; kstep++)
            aq[mt][kstep] = *(const short8*)(qb + (size_t)(b * TT + qrow + 16 * mt + c) * HS + kstep * 32 + quad * 8);

    const int lastkt = 2 * qt + 1;             // last key-tile with any work
    const int nkt = (lastkt >= j) ? ((lastkt - j) / KSPLIT) + 1 : 0;
    const unsigned short* Ktiles = kbt + (size_t)b * 64 * 4096;
    const unsigned short* Vtiles = vTt + (size_t)b * 64 * 4096;

// 4 linear 4KB DMA strips: whole 8KB K-tile + 8KB V-tile into kv[BUF]
#define STAGE(BUF, KT) do { \
    size_t o_ = (size_t)(KT) * 4096 + t * 8; \
    g2lds16(Ktiles + o_,        &kv[BUF][0][w * 512]); \
    g2lds16(Ktiles + o_ + 2048, &kv[BUF][0][2048 + w * 512]); \
    g2lds16(Vtiles + o_,        &kv[BUF][1][w * 512]); \
    g2lds16(Vtiles + o_ + 2048, &kv[BUF][1][2048 + w * 512]); } while (0)

    float l[2] = {0.f, 0.f};
    f32x4 oacc[2][4];
    #pragma unroll
    for (int mt = 0; mt < 2; mt++)
        #pragma unroll
        for (int dt = 0; dt < 4; dt++) oacc[mt][dt] = (f32x4){0.f, 0.f, 0.f, 0.f};

// Full tile: swapped QK^T -> masked exp2 -> in-register repack -> PV.
// S^T layout: lane(quad,c) reg r of s4[mt][st] = S[key=kt0+16st+4quad+r][q=qrow+16mt+c]
#define TILE(CB, DOMASK) do { \
    f32x4 s4[2][4]; \
    _Pragma("unroll") \
    for (int mt_ = 0; mt_ < 2; mt_++) \
        _Pragma("unroll") \
        for (int st_ = 0; st_ < 4; st_++) s4[mt_][st_] = (f32x4){0.f,0.f,0.f,0.f}; \
    _Pragma("unroll") \
    for (int st_ = 0; st_ < 4; st_++) { \
        short8 bf0 = *(const short8*)&kv[CB][0][(16 * st_ + c) * 64 + csw0]; \
        short8 bf1 = *(const short8*)&kv[CB][0][(16 * st_ + c) * 64 + csw1]; \
        __builtin_amdgcn_s_setprio(1); \
        s4[0][st_] = __builtin_amdgcn_mfma_f32_16x16x32_bf16(bf0, aq[0][0], s4[0][st_], 0, 0, 0); \
        s4[1][st_] = __builtin_amdgcn_mfma_f32_16x16x32_bf16(bf0, aq[1][0], s4[1][st_], 0, 0, 0); \
        s4[0][st_] = __builtin_amdgcn_mfma_f32_16x16x32_bf16(bf1, aq[0][1], s4[0][st_], 0, 0, 0); \
        s4[1][st_] = __builtin_amdgcn_mfma_f32_16x16x32_bf16(bf1, aq[1][1], s4[1][st_], 0, 0, 0); \
        __builtin_amdgcn_s_setprio(0); \
    } \
    short8 ap[2][2]; \
    _Pragma("unroll") \
    for (int mt_ = 0; mt_ < 2; mt_++) { \
        const int qg_ = qrow + 16 * mt_ + c; (void)qg_; \
        unsigned Wp[4][2]; \
        _Pragma("unroll") \
        for (int st_ = 0; st_ < 4; st_++) { \
            float pv_[4]; \
            _Pragma("unroll") \
            for (int r_ = 0; r_ < 4; r_++) { \
                float e_ = __builtin_amdgcn_exp2f(s4[mt_][st_][r_]); \
                if (DOMASK) { \
                    int kg_ = kt0 + 16 * st_ + 4 * quad + r_; \
                    if (kg_ > qg_) e_ = 0.f; \
                } \
                pv_[r_] = e_; l[mt_] += e_; \
            } \
            Wp[st_][0] = cvt_pk_bf16(pv_[0], pv_[1]); \
            Wp[st_][1] = cvt_pk_bf16(pv_[2], pv_[3]); \
        } \
        asm volatile("s_nop 1\nv_permlane32_swap_b32 %0, %1\ns_nop 1" : "+v"(Wp[0][0]), "+v"(Wp[1][0])); \
        asm volatile("v_permlane32_swap_b32 %0, %1\ns_nop 1" : "+v"(Wp[0][1]), "+v"(Wp[1][1])); \
        asm volatile("v_permlane32_swap_b32 %0, %1\ns_nop 1" : "+v"(Wp[2][0]), "+v"(Wp[3][0])); \
        asm volatile("v_permlane32_swap_b32 %0, %1\ns_nop 1" : "+v"(Wp[2][1]), "+v"(Wp[3][1])); \
        union UW_ { unsigned u[4]; short8 s; } u0_, u1_; \
        u0_.u[0] = Wp[0][0]; u0_.u[1] = Wp[0][1]; u0_.u[2] = Wp[1][0]; u0_.u[3] = Wp[1][1]; \
        u1_.u[0] = Wp[2][0]; u1_.u[1] = Wp[2][1]; u1_.u[2] = Wp[3][0]; u1_.u[3] = Wp[3][1]; \
        ap[mt_][0] = u0_.s; ap[mt_][1] = u1_.s; \
    } \
    __builtin_amdgcn_s_setprio(1); \
    _Pragma("unroll") \
    for (int ks_ = 0; ks_ < 2; ks_++) { \
        const int csw_ = ks_ ? csw1 : csw0; \
        _Pragma("unroll") \
        for (int dt_ = 0; dt_ < 4; dt_++) { \
            short8 bv = *(const short8*)&kv[CB][1][(16 * dt_ + c) * 64 + csw_]; \
            oacc[0][dt_] = __builtin_amdgcn_mfma_f32_16x16x32_bf16(ap[0][ks_], bv, oacc[0][dt_], 0, 0, 0); \
            oacc[1][dt_] = __builtin_amdgcn_mfma_f32_16x16x32_bf16(ap[1][ks_], bv, oacc[1][dt_], 0, 0, 0); \
        } \
    } \
    __builtin_amdgcn_s_setprio(0); \
} while (0)

    if (nkt > 0) STAGE(0, j);
    __syncthreads();                             // tile 0 staged

    for (int i = 0; i < nkt; i++) {
        const int cb = i & 1;
        const int kt = j + KSPLIT * i;
        const int kt0 = kt * 64;

        // issue next tile's DMA FIRST (overlaps this tile's compute)
        if (i + 1 < nkt) STAGE(cb ^ 1, kt + KSPLIT);

        // wave-uniform skip: tile entirely above this wave's diagonal
        if (kt0 <= qrow + 31) {
            if (kt >= 2 * qt) {
                TILE(cb, 1);                     // diagonal-adjacent: mask
            } else {
                TILE(cb, 0);                     // interior: no mask
            }
        }

        __syncthreads();   // ONE barrier/tile: drains DMA, closes compute
    }
#undef TILE
#undef STAGE

    // ---- epilogue: sum l over the 4 quads, write bf16 unnormalized partials
    l[0] += __shfl_xor(l[0], 16); l[0] += __shfl_xor(l[0], 32);
    l[1] += __shfl_xor(l[1], 16); l[1] += __shfl_xor(l[1], 32);

    unsigned short* __restrict__ Oj = Opart + (size_t)j * MM * HS;
    #pragma unroll
    for (int mt = 0; mt < 2; mt++)
        #pragma unroll
        for (int dt = 0; dt < 4; dt++)
            #pragma unroll
            for (int reg = 0; reg < 4; reg++)
                Oj[(size_t)(b * TT + qrow + 16 * mt + quad * 4 + reg) * HS + 16 * dt + c] = f2bf(oacc[mt][dt][reg]);
    if (lane < 16) {
        lpart[(size_t)j * MM + b * TT + qrow + lane]      = l[0];
        lpart[(size_t)j * MM + b * TT + qrow + 16 + lane] = l[1];
    }
}

// ---------------------------------------------------------------------------
// combine: out = (sum_j O_j) / (sum_j l_j), j=0..7; O_j stored bf16.
// Thread handles 8 consecutive d (16B bf16 read per j, 32B fp32 write).
// Grid 512 x 256. bf16->fp32 is exact (u<<16); sums in fp32.
// ---------------------------------------------------------------------------
__global__ __launch_bounds__(256) void combine_kernel(
    const unsigned short* __restrict__ Opart, const float* __restrict__ lpart,
    float* __restrict__ out)
{
    const int id = blockIdx.x * 256 + threadIdx.x;   // 0 .. MM*HS/8-1
    const int row = id >> 3;
    const int d0 = (id & 7) * 8;
    float l = 0.f;
    #pragma unroll
    for (int j = 0; j < KSPLIT; j++) l += lpart[(size_t)j * MM + row];
    const size_t stride = (size_t)MM * HS;
    const size_t base = (size_t)row * HS + d0;
    float acc[8] = {0.f, 0.f, 0.f, 0.f, 0.f, 0.f, 0.f, 0.f};
    #pragma unroll
    for (int j = 0; j < KSPLIT; j++) {
        short8 v = *(const short8*)(Opart + (size_t)j * stride + base);
        #pragma unroll
        for (int k = 0; k < 8; k++) {
            union { unsigned u; float f; } cv;
            cv.u = ((unsigned)(unsigned short)v[k]) << 16;   // bf16->f32 exact
            acc[k] += cv.f;
        }
    }
    const float inv = 1.f / l;
    float4 r0 = { acc[0] * inv, acc[1] * inv, acc[2] * inv, acc[3] * inv };
    float4 r1 = { acc[4] * inv, acc[5] * inv, acc[6] * inv, acc[7] * inv };
    *(float4*)(out + base) = r0;
    *(float4*)(out + base + 4) = r1;
}

extern "C" void kernel_launch(void* const* d_in, const int* in_sizes, int n_in,
                              void* d_out, int out_size, void* d_ws, size_t ws_size,
                              hipStream_t stream) {
    const float* x  = (const float*)d_in[0];
    const float* Wq = (const float*)d_in[1];
    const float* Wk = (const float*)d_in[2];
    const float* Wv = (const float*)d_in[3];
    float* out = (float*)d_out;

    unsigned short* Wt   = (unsigned short*)d_ws;            // 384 KB (swizzled)
    unsigned short* qbuf = Wt + 3 * 64 * 1024;               // 2 MB each
    unsigned short* kbt  = qbuf + (size_t)MM * HS;           // tiled+swizzled K
    unsigned short* vTt  = kbt + (size_t)MM * HS;            // tiled+swizzled+permuted V^T
    unsigned short* Opart = vTt + (size_t)MM * HS;           // 8 x 2 MB (bf16)
    float* lpart = (float*)(Opart + (size_t)KSPLIT * MM * HS);  // 512 KB

    prep_kernel<<<48, 256, 0, stream>>>(Wq, Wk, Wv, Wt);
    qkv_mfma<<<MM / 32, 256, 0, stream>>>(x, Wt, qbuf, kbt, vTt);
    attn_mfma<<<BB * (TT / 128) * KSPLIT, 256, 0, stream>>>(qbuf, kbt, vTt, Opart, lpart);
    combine_kernel<<<MM * HS / 8 / 256, 256, 0, stream>>>(Opart, lpart, out);
}